// Round 16
// baseline (161.776 us; speedup 1.0000x reference)
//
#include <hip/hip_runtime.h>
#include <hip/hip_bf16.h>
#include <stdint.h>

// Problem constants
#define Bq 8
#define Lq 2048
#define Dq 1024
#define Pq 4
#define Kq 4096          // D*P
#define LPAD 2056        // 3 zero rows + 2048 data + 5 slack, per batch
// GEMM: 256x256, BK=64, 8 waves. A staged in LDS (64 KiB dbuf);
// B pre-packed in fragment order, loaded HBM/L2 -> registers directly.
#define BM 256
#define BN 256
#define BK 64

typedef __attribute__((ext_vector_type(8))) short short8;   // 8 bf16 (4 VGPRs)
typedef __attribute__((ext_vector_type(4))) float f32x4;

__device__ __forceinline__ unsigned short f2bf(float f) {
  unsigned u = __float_as_uint(f);
  u += 0x7FFFu + ((u >> 16) & 1u);   // round-to-nearest-even
  return (unsigned short)(u >> 16);
}

__device__ __forceinline__ void gload_lds16(const void* g, void* l) {
  __builtin_amdgcn_global_load_lds(
      (const __attribute__((address_space(1))) void*)g,
      (__attribute__((address_space(3))) void*)l, 16, 0, 0);
}

// ---- merged prep ----
// blocks [0,8224): xp[b][r][d] = (3 <= r < 2051) ? bf16(x[b][r-3][d]) : 0
// blocks [8224,10272): pack W into B-fragment order:
//   Wf group g=(d>>6)*64+kt (8192 B): slot s=kk*4+ni (1024 B): lane l (16 B)
//   holds B[col=(d>>6)*64+ni*16+(l&15)][k=kt*64+kk*32+(l>>4)*8 .. +8]
__global__ void k_prep(const float* __restrict__ x, const float* __restrict__ W,
                       unsigned short* __restrict__ xp, unsigned short* __restrict__ Wf) {
  if (blockIdx.x < 8224u) {
    unsigned g = blockIdx.x * blockDim.x + threadIdx.x;
    unsigned base = g * 8;
    const unsigned total = (unsigned)Bq * LPAD * Dq;
    if (base >= total) return;
    unsigned t = base >> 10;            // b*LPAD + r
    unsigned b = t / LPAD;
    unsigned r = t - b * LPAD;
    unsigned d = base & 1023;
    short8 o;
    if (r >= 3 && r < 3 + Lq) {
      const float* s = x + ((size_t)b * Lq + (r - 3)) * Dq + d;
      float4 v0 = *(const float4*)(s);
      float4 v1 = *(const float4*)(s + 4);
      o[0] = (short)f2bf(v0.x); o[1] = (short)f2bf(v0.y);
      o[2] = (short)f2bf(v0.z); o[3] = (short)f2bf(v0.w);
      o[4] = (short)f2bf(v1.x); o[5] = (short)f2bf(v1.y);
      o[6] = (short)f2bf(v1.z); o[7] = (short)f2bf(v1.w);
    } else {
      o = (short8)0;
    }
    *(short8*)(xp + base) = o;
  } else {
    unsigned g = (blockIdx.x - 8224u) * blockDim.x + threadIdx.x;  // 0..524287
    unsigned d  = g >> 9;              // 0..1023
    unsigned kc = g & 511;             // 8-k chunk: k0 = kc*8 = i*1024 + dp0+e
    unsigned i  = kc >> 7;             // phrase offset 0..3
    unsigned dp0 = (kc & 127) << 3;
    const float* src = W + (size_t)d * 4096 + (size_t)dp0 * 4 + i;
    short8 o;
#pragma unroll
    for (int e = 0; e < 8; ++e) o[e] = (short)f2bf(src[e * 4]);
    unsigned kt = kc >> 3;
    unsigned kk = (kc >> 2) & 1;
    unsigned ni = (d >> 4) & 3;
    unsigned lane = (d & 15) + ((kc & 3) << 4);
    unsigned a16 = ((((d >> 6) * 64 + kt) * 8) + kk * 4 + ni) * 64 + lane;
    *(short8*)(Wf + ((size_t)a16 << 3)) = o;
  }
}

// ====== 256x256 GEMM: A via LDS (dbuf 64 KiB), B direct-to-register ======
// C[m][n] = sum_k A[m][k]*Wf-frag + bias[n],  A[m][i*1024+d'] = xp[b][l+3-i][d']
// LDS: A buf0 @0, buf1 @32768; tile row r (0..255) at r*128B;
//   byte within row: SWIZZLED phys_c = log_c ^ ((r&7)<<4).
// 8 waves: wm=w>>2 (rows wm*128), wn=w&3 (cols wn*64).
// Per tile T (buf p=T&1), 2 phases:
//  phA: [8 B-loads (T)][stage (T+1)h1 -> p^1 (2 gl)][8 ds_read A0(p)]
//       VM2 (drain B + (T+1)h0; leave (T+1)h1); MFMA Q0*; BAR
//  phB: [stage (T+2)h0 -> p (2 gl)][8 ds_read A1(p)]; MFMA Q1*; BAR
// Ledger @VM2 of phA(T): oldest->newest = (T+1)h0(2) | B(T)(8) | (T+1)h1(2);
// VM2 leaves (T+1)h1 -> h0 published (read phA(T+1)); h1 drains at VM2 of
// phA(T+1) before its phB read. WAR: stage (T+2)h0 hits A0(T) region one
// barrier after its last read (phA(T)); (T+1)h1 hits (T-1)h1 region one
// barrier after phB(T-1). B-frag regs overwritten at phA(T+1) after phB(T)
// MFMAs (same-wave program order).

#define VM2 asm volatile("s_waitcnt vmcnt(2)" ::: "memory")
#define VM0 asm volatile("s_waitcnt vmcnt(0)" ::: "memory")
#define BAR __builtin_amdgcn_s_barrier()

#define LOAD_B(kt) do { \
    const unsigned short* wb_ = Wf + (((unsigned)(nIdx64 + (kt))) << 12); \
    _Pragma("unroll") for (int s_ = 0; s_ < 8; ++s_) \
      bF[s_ & 3][s_ >> 2] = *(const short8*)(wb_ + (s_ << 9) + lan8); \
  } while (0)

// stage half h of tile kt into buf: 2 gloads x 512 thr x 16B = 16 KB (64 rows each)
#define STAGE_H(buf, kt, h) do { \
    const unsigned sclA_ = (((unsigned)(bRow0 - ((kt) >> 4))) << 11) + (((unsigned)(kt) & 15u) << 7); \
    _Pragma("unroll") for (int q_ = 0; q_ < 2; ++q_) { \
      const int qq_ = (h) * 2 + q_; \
      gload_lds16((const char*)xp + (thrA + (unsigned)(qq_ << 17) + sclA_), \
                  lds + ((buf) << 15) + (qq_ << 13) + (tid << 4)); \
    } } while (0)

#define RD_A(buf, h) do { \
    _Pragma("unroll") for (int mi_ = 0; mi_ < 4; ++mi_) \
    _Pragma("unroll") for (int kk_ = 0; kk_ < 2; ++kk_) \
      fa[mi_][kk_] = *(const short8*)(lds + (((buf) << 15) + ((h) << 13)) + aRC[mi_][kk_]); \
  } while (0)

#define MFMAQ(mh) do { \
    __builtin_amdgcn_s_setprio(1); \
    _Pragma("unroll") for (int kk_ = 0; kk_ < 2; ++kk_) \
    _Pragma("unroll") for (int mi_ = 0; mi_ < 4; ++mi_) \
    _Pragma("unroll") for (int ni_ = 0; ni_ < 4; ++ni_) \
      acc[(mh) * 4 + mi_][ni_] = __builtin_amdgcn_mfma_f32_16x16x32_bf16( \
          fa[mi_][kk_], bF[ni_][kk_], acc[(mh) * 4 + mi_][ni_], 0, 0, 0); \
    __builtin_amdgcn_s_setprio(0); \
  } while (0)

__global__ void __launch_bounds__(512, 2)
k_gemm(const unsigned short* __restrict__ xp,
       const unsigned short* __restrict__ Wf,
       const float* __restrict__ bias,
       float* __restrict__ out) {
  __shared__ __attribute__((aligned(16))) unsigned char lds[65536];

  const int tid  = threadIdx.x;
  const int lane = tid & 63;
  const int w    = tid >> 6;       // 0..7
  const int wm   = w >> 2;         // 0..1
  const int wn   = w & 3;          // 0..3

  // bijective XCD swizzle (256 blocks): each XCD a contiguous 8m x 4n chunk.
  const int bid = blockIdx.x;
  const int swz = (bid & 7) * 32 + (bid >> 3);
  const int m0 = (swz >> 2) * BM;
  const int n0 = (swz & 3) * BN;
  const int b  = m0 >> 11;
  const int l0 = m0 & 2047;
  const int bRow0 = b * LPAD + l0 + 3;                 // SGPR
  const unsigned nIdx64 = (unsigned)(((n0 >> 6) + wn)) << 6;  // n64-group * 64
  const unsigned lan8 = (unsigned)lane << 3;           // lane*16B in elems

  // ---- A staging per-thread invariants (512 thr, 64 rows/gload) ----
  const unsigned srow = (unsigned)(tid >> 3);                       // 0..63
  const unsigned clog = ((unsigned)((tid & 7) ^ ((tid >> 3) & 7))); // chunk
  const unsigned thrA = (srow << 11) + (clog << 4);                 // bytes

  // ---- A ds_read addresses ----
  unsigned aRC[4][2];
  {
#pragma unroll
    for (int mi = 0; mi < 4; ++mi)
#pragma unroll
      for (int kk = 0; kk < 2; ++kk) {
        const int cb = (kk * 64 + ((lane >> 4) << 4)) ^ ((lane & 7) << 4);
        aRC[mi][kk] = (unsigned)((wm << 14) + ((mi * 16 + (lane & 15)) << 7) + cb);
      }
  }

  f32x4 acc[8][4] = {};
  short8 fa[4][2], bF[4][2];

  // ---- prologue: stage t0 (h0+h1) + t1 h0 = 6 gloads ----
  STAGE_H(0, 0, 0);
  STAGE_H(0, 0, 1);
  STAGE_H(1, 1, 0);
  VM2;                               // drain t0 (leaves t1h0)
  BAR;

  // ---- main loop: 31 iters, tiles T=2it (buf0), U=T+1 (buf1) ----
#pragma unroll 1
  for (int it = 0; it < 31; ++it) {
    const int T = it * 2;
    // phA(T)
    LOAD_B(T);
    STAGE_H(1, T + 1, 1);
    RD_A(0, 0);
    VM2; MFMAQ(0); BAR;
    // phB(T)
    STAGE_H(0, T + 2, 0);
    RD_A(0, 1);
    MFMAQ(1); BAR;
    // phA(U)
    LOAD_B(T + 1);
    STAGE_H(0, T + 2, 1);
    RD_A(1, 0);
    VM2; MFMAQ(0); BAR;
    // phB(U)
    STAGE_H(1, T + 3, 0);
    RD_A(1, 1);
    MFMAQ(1); BAR;
  }

  // ---- tail: tiles 62 (buf0), 63 (buf1) ----
  // phA(62)
  LOAD_B(62);
  STAGE_H(1, 63, 1);
  RD_A(0, 0);
  VM2; MFMAQ(0); BAR;
  // phB(62)
  RD_A(0, 1);
  MFMAQ(1); BAR;
  // phA(63)
  LOAD_B(63);
  RD_A(1, 0);
  VM0; MFMAQ(0); BAR;
  // phB(63)
  RD_A(1, 1);
  MFMAQ(1);

  // ---- C write: col = lane&15, row = (lane>>4)*4 + reg ----
#pragma unroll
  for (int nig = 0; nig < 4; ++nig) {
    const int col = n0 + wn * 64 + nig * 16 + (lane & 15);
    const float bv = bias[col];
#pragma unroll
    for (int mig = 0; mig < 8; ++mig) {
      const int row0 = m0 + wm * 128 + mig * 16 + ((lane >> 4) << 2);
#pragma unroll
      for (int t2 = 0; t2 < 4; ++t2)
        out[(size_t)(row0 + t2) * Dq + col] = acc[mig][nig][t2] + bv;
    }
  }
}

// ---- slow-but-correct fallback if workspace is too small ----
__global__ void k_naive(const float* __restrict__ x, const float* __restrict__ W,
                        const float* __restrict__ bias, float* __restrict__ out) {
  size_t g = (size_t)blockIdx.x * blockDim.x + threadIdx.x;
  const size_t total = (size_t)Bq * Lq * Dq;
  if (g >= total) return;
  int d = (int)(g & 1023);
  int l = (int)((g >> 10) & 2047);
  int b = (int)(g >> 21);
  float s = bias[d];
  for (int i = 0; i < Pq; ++i) {
    if (l - i < 0) continue;
    const float* xr = x + ((size_t)b * Lq + (l - i)) * Dq;
    const float* wr = W + (size_t)d * Kq + i;
    float accv = 0.f;
    for (int dp = 0; dp < Dq; ++dp) accv += xr[dp] * wr[(size_t)dp * 4];
    s += accv;
  }
  out[g] = s;
}

extern "C" void kernel_launch(void* const* d_in, const int* in_sizes, int n_in,
                              void* d_out, int out_size, void* d_ws, size_t ws_size,
                              hipStream_t stream) {
  const float* x    = (const float*)d_in[0];
  const float* W    = (const float*)d_in[1];
  const float* bias = (const float*)d_in[2];
  float* out = (float*)d_out;

  const size_t WF_BYTES = (size_t)Dq * Kq * sizeof(unsigned short);        // 8 MiB
  const size_t XP_BYTES = (size_t)Bq * LPAD * Dq * sizeof(unsigned short); // ~33.7 MB

  if (ws_size < WF_BYTES + XP_BYTES) {
    const size_t total = (size_t)Bq * Lq * Dq;
    k_naive<<<(unsigned)((total + 255) / 256), 256, 0, stream>>>(x, W, bias, out);
    return;
  }

  unsigned short* Wf = (unsigned short*)d_ws;
  unsigned short* xp = (unsigned short*)((char*)d_ws + WF_BYTES);

  k_prep<<<10272, 256, 0, stream>>>(x, W, xp, Wf);
  k_gemm<<<dim3((Bq * Lq / BM) * (Dq / BN)), 512, 0, stream>>>(xp, Wf, bias, out);
}

// Round 17
// 156.828 us; speedup vs baseline: 1.0316x; 1.0316x over previous
//
#include <hip/hip_runtime.h>
#include <hip/hip_bf16.h>
#include <stdint.h>

// Problem constants
#define Bq 8
#define Lq 2048
#define Dq 1024
#define Pq 4
#define Kq 4096          // D*P
#define LPAD 2056        // 3 zero rows + 2048 data + 5 slack, per batch
// GEMM: 256x256, BK=64, 8 waves. A staged in LDS (64 KiB dbuf);
// B pre-packed in fragment order, loaded L2->registers ONE TILE AHEAD
// (issued after its predecessor's last use -> latency crosses the barrier).
#define BM 256
#define BN 256
#define BK 64

typedef __attribute__((ext_vector_type(8))) short short8;   // 8 bf16 (4 VGPRs)
typedef __attribute__((ext_vector_type(4))) float f32x4;

__device__ __forceinline__ unsigned short f2bf(float f) {
  unsigned u = __float_as_uint(f);
  u += 0x7FFFu + ((u >> 16) & 1u);   // round-to-nearest-even
  return (unsigned short)(u >> 16);
}

__device__ __forceinline__ void gload_lds16(const void* g, void* l) {
  __builtin_amdgcn_global_load_lds(
      (const __attribute__((address_space(1))) void*)g,
      (__attribute__((address_space(3))) void*)l, 16, 0, 0);
}

// ---- merged prep ----
// blocks [0,8224): xp[b][r][d] = (3 <= r < 2051) ? bf16(x[b][r-3][d]) : 0
// blocks [8224,10272): pack W into B-fragment order:
//   Wf group g=(d>>6)*64+kt (8192 B): slot s=kk*4+ni (1024 B): lane l (16 B)
//   holds B[col=(d>>6)*64+ni*16+(l&15)][k=kt*64+kk*32+(l>>4)*8 .. +8]
__global__ void k_prep(const float* __restrict__ x, const float* __restrict__ W,
                       unsigned short* __restrict__ xp, unsigned short* __restrict__ Wf) {
  if (blockIdx.x < 8224u) {
    unsigned g = blockIdx.x * blockDim.x + threadIdx.x;
    unsigned base = g * 8;
    const unsigned total = (unsigned)Bq * LPAD * Dq;
    if (base >= total) return;
    unsigned t = base >> 10;            // b*LPAD + r
    unsigned b = t / LPAD;
    unsigned r = t - b * LPAD;
    unsigned d = base & 1023;
    short8 o;
    if (r >= 3 && r < 3 + Lq) {
      const float* s = x + ((size_t)b * Lq + (r - 3)) * Dq + d;
      float4 v0 = *(const float4*)(s);
      float4 v1 = *(const float4*)(s + 4);
      o[0] = (short)f2bf(v0.x); o[1] = (short)f2bf(v0.y);
      o[2] = (short)f2bf(v0.z); o[3] = (short)f2bf(v0.w);
      o[4] = (short)f2bf(v1.x); o[5] = (short)f2bf(v1.y);
      o[6] = (short)f2bf(v1.z); o[7] = (short)f2bf(v1.w);
    } else {
      o = (short8)0;
    }
    *(short8*)(xp + base) = o;
  } else {
    unsigned g = (blockIdx.x - 8224u) * blockDim.x + threadIdx.x;  // 0..524287
    unsigned d  = g >> 9;              // 0..1023
    unsigned kc = g & 511;             // 8-k chunk: k0 = kc*8 = i*1024 + dp0+e
    unsigned i  = kc >> 7;             // phrase offset 0..3
    unsigned dp0 = (kc & 127) << 3;
    const float* src = W + (size_t)d * 4096 + (size_t)dp0 * 4 + i;
    short8 o;
#pragma unroll
    for (int e = 0; e < 8; ++e) o[e] = (short)f2bf(src[e * 4]);
    unsigned kt = kc >> 3;
    unsigned kk = (kc >> 2) & 1;
    unsigned ni = (d >> 4) & 3;
    unsigned lane = (d & 15) + ((kc & 3) << 4);
    unsigned a16 = ((((d >> 6) * 64 + kt) * 8) + kk * 4 + ni) * 64 + lane;
    *(short8*)(Wf + ((size_t)a16 << 3)) = o;
  }
}

// ====== 256x256 GEMM: A via LDS (dbuf 64 KiB), B L2->reg one tile ahead ======
// C[m][n] = sum_k A[m][k]*Wf-frag + bias[n],  A[m][i*1024+d'] = xp[b][l+3-i][d']
// LDS: A buf0 @0, buf1 @32768; tile row r (0..255) at r*128B;
//   byte within row: SWIZZLED phys_c = log_c ^ ((r&7)<<4).
// 8 waves: wm=w>>2 (rows wm*128), wn=w&3 (cols wn*64).
// Per tile T (buf p=T&1):
//  phA: [stage (T+1)h1 -> p^1][8 ds_read A0(p)]; VM2; MFMA Q0*; BAR
//  phB: [stage (T+2)h0 -> p][8 ds_read A1(p)]; MFMA Q1*; LOAD_B(T+1); BAR
// Ledger @VM2 of phA(T), oldest->newest:
//   st(T,h1)2 | st(T+1,h0)2 | B(T)8 | st(T+1,h1)2  -> VM2 drains st(T,h1)
//   (read phB(T)), st(T+1,h0) (read phA(T+1)), B(T) (MFMAQ(0) right after);
//   leaves st(T+1,h1) in flight across the MFMAs. B(T) was issued BEFORE
//   phB(T-1)'s barrier -> its L2 latency is covered by BAR + issue window.
// WAR: each stage targets a region whose last reads completed before the
// preceding barrier (compiler lgkm before same-phase MFMA use). LOAD_B(T+1)
// overwrites bF only after MFMAQ(1)'s last read (program order, same wave).

#define VM2 asm volatile("s_waitcnt vmcnt(2)" ::: "memory")
#define VM0 asm volatile("s_waitcnt vmcnt(0)" ::: "memory")
#define BAR __builtin_amdgcn_s_barrier()

#define LOAD_B(kt) do { \
    const unsigned short* wb_ = Wf + (((unsigned)(nIdx64 + (kt))) << 12); \
    _Pragma("unroll") for (int s_ = 0; s_ < 8; ++s_) \
      bF[s_ & 3][s_ >> 2] = *(const short8*)(wb_ + (s_ << 9) + lan8); \
  } while (0)

// stage half h of tile kt into buf: 2 gloads x 512 thr x 16B = 16 KB (64 rows each)
#define STAGE_H(buf, kt, h) do { \
    const unsigned sclA_ = (((unsigned)(bRow0 - ((kt) >> 4))) << 11) + (((unsigned)(kt) & 15u) << 7); \
    _Pragma("unroll") for (int q_ = 0; q_ < 2; ++q_) { \
      const int qq_ = (h) * 2 + q_; \
      gload_lds16((const char*)xp + (thrA + (unsigned)(qq_ << 17) + sclA_), \
                  lds + ((buf) << 15) + (qq_ << 13) + (tid << 4)); \
    } } while (0)

#define RD_A(buf, h) do { \
    _Pragma("unroll") for (int mi_ = 0; mi_ < 4; ++mi_) \
    _Pragma("unroll") for (int kk_ = 0; kk_ < 2; ++kk_) \
      fa[mi_][kk_] = *(const short8*)(lds + (((buf) << 15) + ((h) << 13)) + aRC[mi_][kk_]); \
  } while (0)

#define MFMAQ(mh) do { \
    __builtin_amdgcn_s_setprio(1); \
    _Pragma("unroll") for (int kk_ = 0; kk_ < 2; ++kk_) \
    _Pragma("unroll") for (int mi_ = 0; mi_ < 4; ++mi_) \
    _Pragma("unroll") for (int ni_ = 0; ni_ < 4; ++ni_) \
      acc[(mh) * 4 + mi_][ni_] = __builtin_amdgcn_mfma_f32_16x16x32_bf16( \
          fa[mi_][kk_], bF[ni_][kk_], acc[(mh) * 4 + mi_][ni_], 0, 0, 0); \
    __builtin_amdgcn_s_setprio(0); \
  } while (0)

__global__ void __launch_bounds__(512, 2)
k_gemm(const unsigned short* __restrict__ xp,
       const unsigned short* __restrict__ Wf,
       const float* __restrict__ bias,
       float* __restrict__ out) {
  __shared__ __attribute__((aligned(16))) unsigned char lds[65536];

  const int tid  = threadIdx.x;
  const int lane = tid & 63;
  const int w    = tid >> 6;       // 0..7
  const int wm   = w >> 2;         // 0..1
  const int wn   = w & 3;          // 0..3

  // bijective XCD swizzle (256 blocks): each XCD a contiguous 8m x 4n chunk.
  const int bid = blockIdx.x;
  const int swz = (bid & 7) * 32 + (bid >> 3);
  const int m0 = (swz >> 2) * BM;
  const int n0 = (swz & 3) * BN;
  const int b  = m0 >> 11;
  const int l0 = m0 & 2047;
  const int bRow0 = b * LPAD + l0 + 3;                 // SGPR
  const unsigned nIdx64 = (unsigned)(((n0 >> 6) + wn)) << 6;  // n64-group * 64
  const unsigned lan8 = (unsigned)lane << 3;           // lane*16B in elems

  // ---- A staging per-thread invariants (512 thr, 64 rows/gload) ----
  const unsigned srow = (unsigned)(tid >> 3);                       // 0..63
  const unsigned clog = ((unsigned)((tid & 7) ^ ((tid >> 3) & 7))); // chunk
  const unsigned thrA = (srow << 11) + (clog << 4);                 // bytes

  // ---- A ds_read addresses ----
  unsigned aRC[4][2];
  {
#pragma unroll
    for (int mi = 0; mi < 4; ++mi)
#pragma unroll
      for (int kk = 0; kk < 2; ++kk) {
        const int cb = (kk * 64 + ((lane >> 4) << 4)) ^ ((lane & 7) << 4);
        aRC[mi][kk] = (unsigned)((wm << 14) + ((mi * 16 + (lane & 15)) << 7) + cb);
      }
  }

  f32x4 acc[8][4] = {};
  short8 fa[4][2], bF[4][2];

  // ---- prologue: stage t0 (h0+h1) + t1 h0; B(0) -> regs; drain all ----
  STAGE_H(0, 0, 0);
  STAGE_H(0, 0, 1);
  STAGE_H(1, 1, 0);
  LOAD_B(0);
  VM0;
  BAR;

  // ---- main loop: 31 iters, tiles T=2it (buf0), U=T+1 (buf1) ----
#pragma unroll 1
  for (int it = 0; it < 31; ++it) {
    const int T = it * 2;
    // phA(T)
    STAGE_H(1, T + 1, 1);
    RD_A(0, 0);
    VM2; MFMAQ(0); BAR;
    // phB(T)
    STAGE_H(0, T + 2, 0);
    RD_A(0, 1);
    MFMAQ(1);
    LOAD_B(T + 1);                   // bF dead after MFMAQ(1); covers BAR+phA
    BAR;
    // phA(U)
    STAGE_H(0, T + 2, 1);
    RD_A(1, 0);
    VM2; MFMAQ(0); BAR;
    // phB(U)
    STAGE_H(1, T + 3, 0);
    RD_A(1, 1);
    MFMAQ(1);
    LOAD_B(T + 2);
    BAR;
  }

  // ---- tail: tiles 62 (buf0), 63 (buf1) ----
  // phA(62)
  STAGE_H(1, 63, 1);
  RD_A(0, 0);
  VM2; MFMAQ(0); BAR;
  // phB(62)
  RD_A(0, 1);
  MFMAQ(1);
  LOAD_B(63);
  BAR;
  // phA(63)
  RD_A(1, 0);
  VM0; MFMAQ(0); BAR;
  // phB(63)
  RD_A(1, 1);
  MFMAQ(1);

  // ---- C write: col = lane&15, row = (lane>>4)*4 + reg ----
#pragma unroll
  for (int nig = 0; nig < 4; ++nig) {
    const int col = n0 + wn * 64 + nig * 16 + (lane & 15);
    const float bv = bias[col];
#pragma unroll
    for (int mig = 0; mig < 8; ++mig) {
      const int row0 = m0 + wm * 128 + mig * 16 + ((lane >> 4) << 2);
#pragma unroll
      for (int t2 = 0; t2 < 4; ++t2)
        out[(size_t)(row0 + t2) * Dq + col] = acc[mig][nig][t2] + bv;
    }
  }
}

// ---- slow-but-correct fallback if workspace is too small ----
__global__ void k_naive(const float* __restrict__ x, const float* __restrict__ W,
                        const float* __restrict__ bias, float* __restrict__ out) {
  size_t g = (size_t)blockIdx.x * blockDim.x + threadIdx.x;
  const size_t total = (size_t)Bq * Lq * Dq;
  if (g >= total) return;
  int d = (int)(g & 1023);
  int l = (int)((g >> 10) & 2047);
  int b = (int)(g >> 21);
  float s = bias[d];
  for (int i = 0; i < Pq; ++i) {
    if (l - i < 0) continue;
    const float* xr = x + ((size_t)b * Lq + (l - i)) * Dq;
    const float* wr = W + (size_t)d * Kq + i;
    float accv = 0.f;
    for (int dp = 0; dp < Dq; ++dp) accv += xr[dp] * wr[(size_t)dp * 4];
    s += accv;
  }
  out[g] = s;
}

extern "C" void kernel_launch(void* const* d_in, const int* in_sizes, int n_in,
                              void* d_out, int out_size, void* d_ws, size_t ws_size,
                              hipStream_t stream) {
  const float* x    = (const float*)d_in[0];
  const float* W    = (const float*)d_in[1];
  const float* bias = (const float*)d_in[2];
  float* out = (float*)d_out;

  const size_t WF_BYTES = (size_t)Dq * Kq * sizeof(unsigned short);        // 8 MiB
  const size_t XP_BYTES = (size_t)Bq * LPAD * Dq * sizeof(unsigned short); // ~33.7 MB

  if (ws_size < WF_BYTES + XP_BYTES) {
    const size_t total = (size_t)Bq * Lq * Dq;
    k_naive<<<(unsigned)((total + 255) / 256), 256, 0, stream>>>(x, W, bias, out);
    return;
  }

  unsigned short* Wf = (unsigned short*)d_ws;
  unsigned short* xp = (unsigned short*)((char*)d_ws + WF_BYTES);

  k_prep<<<10272, 256, 0, stream>>>(x, W, xp, Wf);
  k_gemm<<<dim3((Bq * Lq / BM) * (Dq / BN)), 512, 0, stream>>>(xp, Wf, bias, out);
}